// Round 6
// baseline (832.582 us; speedup 1.0000x reference)
//
#include <hip/hip_runtime.h>

// Paged attention decode, GQA: B=32, H=32, KVH=8 (G=4), D=128, pages of 16.
// R6: token-major scores via wave-private LDS transpose (zero barriers).
//  - One block per (b, part=64 tokens); block covers all 8 kv heads so each
//    physical page is read once, contiguously (R4's proven layout).
//  - Each wave computes 2 kv heads; the coalesced stage assigns each wave
//    exactly its own 2 kvh slices -> LDS slabs are wave-private, no syncthreads.
//  - K transposed through LDS (pad 132 for bank spread): lane owns one token's
//    32-float d-slice -> dot reduce = 2 shfl (was 5 per (tok,g)); softmax is
//    token-parallel (1 exp per head, was 8).
//  - Q staged once per part into wave-private LDS (token-lanes broadcast).
//  - V direct to registers dims-major; P broadcast by shfl for PV.
//  - DIAGNOSTIC: rep x3 loop (idempotent) so attn_partial exceeds the 320us
//    harness fills and shows up in rocprof top-5. Remove next round.

constexpr int Dh   = 128;
constexpr int Gq   = 4;
constexpr int KVH  = 8;
constexpr int Hq   = 32;
constexpr int Bb   = 32;
constexpr int MB   = 256;
constexpr int PAGE = 16;
constexpr float SCALE = 0.08838834764831845f;

constexpr int NPARTS      = 64;
constexpr int PART_TOKENS = 64;                  // 4 pages per part
constexpr int PG_FLOATS   = PAGE * KVH * Dh;     // 16384 floats = 64 KB
constexpr int ROW_FLOATS  = KVH * Dh;            // 1024 floats per token row

// per-(b,part) workspace floats: acc[32 heads][128] + m[32] + l[32]
constexpr int PART_STRIDE = Hq * Dh + 2 * Hq;    // 4160

__global__ __launch_bounds__(256, 3)
void attn_partial(const float* __restrict__ q,
                  const float* __restrict__ kc,
                  const float* __restrict__ vc,
                  const int*   __restrict__ bt,
                  const int*   __restrict__ cl,
                  float*       __restrict__ ws)
{
    const int part = blockIdx.x & (NPARTS - 1);
    const int b    = blockIdx.x >> 6;

    const int ctx    = cl[b];
    const int pstart = part * PART_TOKENS;
    if (pstart >= ctx) return;
    const int n      = min(PART_TOKENS, ctx - pstart);
    const int npages = (n + 15) >> 4;

    const int t      = threadIdx.x;
    const int wave   = t >> 6;
    const int lane   = t & 63;
    const int kvhl   = lane >> 5;                // 0/1: which kvh of the wave's pair
    const int lane32 = lane & 31;
    const int tok    = lane32 & 7;               // my token within a half
    const int d32    = lane32 >> 3;              // my 32-float d-group (0..3)

    // wave-private LDS slabs (no cross-wave sharing -> no barriers anywhere)
    __shared__ float klds[4][2][8][132];         // 33792 B: [wave][kvhl][tok][128+pad]
    __shared__ float qlds[4][2][4][132];         // 16896 B: [wave][kvhl][g][128+pad]

    const int* btrow = bt + b * MB + (pstart >> 4);

    // ---- stage Q for this wave's 8 heads (pre-scaled), wave-private ----
    {
        const float* qb = q + (size_t)b * Hq * Dh;
        #pragma unroll
        for (int i = 0; i < 4; ++i) {
            const int lh  = i * 2 + kvhl;        // local head 0..7
            const int kl  = lh >> 2, g = lh & 3;
            const int dim = lane32 * 4;
            const int gh  = (wave * 2 + kl) * Gq + g;
            float4 x = *(const float4*)(qb + (size_t)gh * Dh + dim);
            *(float4*)&qlds[wave][kl][g][dim] =
                make_float4(x.x * SCALE, x.y * SCALE, x.z * SCALE, x.w * SCALE);
        }
    }

    for (int rep = 0; rep < 3; ++rep) {          // DIAGNOSTIC reps (idempotent)

    float4 acc[Gq];
    float  m_run[Gq], l_run[Gq], p_[Gq];
    #pragma unroll
    for (int g = 0; g < Gq; ++g) {
        acc[g] = make_float4(0.f, 0.f, 0.f, 0.f);
        m_run[g] = -1e30f;
        l_run[g] = 0.f;
    }

    for (int pp = 0; pp < npages; ++pp) {
        const int phys = btrow[pp];
        const size_t pbase = (size_t)phys * PG_FLOATS;

        #pragma unroll
        for (int hsel = 0; hsel < 2; ++hsel) {
            const int tokbase = pp * PAGE + hsel * 8;   // part-local token base
            const size_t goff = pbase + (size_t)(hsel * 8) * ROW_FLOATS + t * 4;

            // K and V halves: coalesced (256 threads x 16B = one 4KB token row)
            float4 kr[8], vr[8];
            #pragma unroll
            for (int i = 0; i < 8; ++i)
                kr[i] = *(const float4*)(kc + goff + (size_t)i * ROW_FLOATS);
            #pragma unroll
            for (int i = 0; i < 8; ++i)
                vr[i] = *(const float4*)(vc + goff + (size_t)i * ROW_FLOATS);

            // transpose K through wave-private LDS (thread's data IS its wave's kvh)
            #pragma unroll
            for (int i = 0; i < 8; ++i)
                *(float4*)&klds[wave][kvhl][i][lane32 * 4] = kr[i];

            // read back token-major: lane owns token `tok`, dims [d32*32, +32)
            float4 kk[8];
            #pragma unroll
            for (int j = 0; j < 8; ++j)
                kk[j] = *(const float4*)&klds[wave][kvhl][tok][d32 * 32 + j * 4];

            const bool tv = (tokbase + tok) < n;

            // scores + online softmax, token-parallel
            #pragma unroll
            for (int g = 0; g < Gq; ++g) {
                float d = 0.f;
                #pragma unroll
                for (int j = 0; j < 8; ++j) {
                    const float4 qj = *(const float4*)&qlds[wave][kvhl][g][d32 * 32 + j * 4];
                    d += kk[j].x * qj.x + kk[j].y * qj.y
                       + kk[j].z * qj.z + kk[j].w * qj.w;
                }
                d += __shfl_xor(d, 8);
                d += __shfl_xor(d, 16);          // full dot, replicated over d32
                d = tv ? d : -1e30f;

                float tm = d;
                tm = fmaxf(tm, __shfl_xor(tm, 1));
                tm = fmaxf(tm, __shfl_xor(tm, 2));
                tm = fmaxf(tm, __shfl_xor(tm, 4));   // max over 8 tokens
                const float mn    = fmaxf(m_run[g], tm);
                const float alpha = __expf(m_run[g] - mn);
                const float pe    = __expf(d - mn);
                float ls = pe;
                ls += __shfl_xor(ls, 1);
                ls += __shfl_xor(ls, 2);
                ls += __shfl_xor(ls, 4);             // sum over 8 tokens
                m_run[g] = mn;
                l_run[g] = l_run[g] * alpha + ls;
                acc[g].x *= alpha; acc[g].y *= alpha;
                acc[g].z *= alpha; acc[g].w *= alpha;
                p_[g] = pe;
            }

            // PV: broadcast p of token j within my (kvhl,d32) octet; V in-lane
            #pragma unroll
            for (int j = 0; j < 8; ++j) {
                const int src = (lane & 0x38) | j;
                #pragma unroll
                for (int g = 0; g < Gq; ++g) {
                    const float pj = __shfl(p_[g], src);
                    acc[g].x = fmaf(pj, vr[j].x, acc[g].x);
                    acc[g].y = fmaf(pj, vr[j].y, acc[g].y);
                    acc[g].z = fmaf(pj, vr[j].z, acc[g].z);
                    acc[g].w = fmaf(pj, vr[j].w, acc[g].w);
                }
            }
        }
    }

    // ---- write partials: head (kvh,g), dims lane32*4 ----
    {
        const int kvh = wave * 2 + kvhl;
        float* wp = ws + (size_t)(b * NPARTS + part) * PART_STRIDE;
        #pragma unroll
        for (int g = 0; g < Gq; ++g)
            *(float4*)(wp + (kvh * Gq + g) * Dh + lane32 * 4) = acc[g];
        if (lane32 == 0) {
            #pragma unroll
            for (int g = 0; g < Gq; ++g) {
                wp[Hq * Dh + kvh * Gq + g]      = m_run[g];
                wp[Hq * Dh + Hq + kvh * Gq + g] = l_run[g];
            }
        }
    }

    }   // rep
}

__global__ __launch_bounds__(256, 4)
void attn_reduce(const float* __restrict__ ws,
                 const int*   __restrict__ cl,
                 float*       __restrict__ out)
{
    const int b       = blockIdx.x >> 2;
    const int quarter = blockIdx.x & 3;
    const int tid     = threadIdx.x;
    const int h       = quarter * 8 + (tid >> 5);
    const int doff    = (tid & 31) * 4;

    const int ctx = cl[b];
    const int np  = min(NPARTS, (ctx + PART_TOKENS - 1) / PART_TOKENS);

    const float* base = ws + (size_t)b * NPARTS * PART_STRIDE;

    float m = -1e30f;
    for (int p = 0; p < np; ++p)
        m = fmaxf(m, base[p * PART_STRIDE + Hq * Dh + h]);

    float L = 0.f;
    float ax = 0.f, ay = 0.f, az = 0.f, aw = 0.f;
    for (int p = 0; p < np; ++p) {
        const float* bp = base + p * PART_STRIDE;
        const float c = __expf(bp[Hq * Dh + h] - m);
        L += bp[Hq * Dh + Hq + h] * c;
        const float4 v = *(const float4*)(bp + h * Dh + doff);
        ax = fmaf(c, v.x, ax);
        ay = fmaf(c, v.y, ay);
        az = fmaf(c, v.z, az);
        aw = fmaf(c, v.w, aw);
    }
    const float inv = 1.f / L;
    float* op = out + (size_t)(b * Hq + h) * Dh + doff;
    *(float4*)op = make_float4(ax * inv, ay * inv, az * inv, aw * inv);
}

extern "C" void kernel_launch(void* const* d_in, const int* in_sizes, int n_in,
                              void* d_out, int out_size, void* d_ws, size_t ws_size,
                              hipStream_t stream) {
    const float* q  = (const float*)d_in[0];
    const float* kc = (const float*)d_in[1];
    const float* vc = (const float*)d_in[2];
    const int*   bt = (const int*)d_in[3];
    const int*   cl = (const int*)d_in[4];
    float* out = (float*)d_out;
    float* ws  = (float*)d_ws;

    attn_partial<<<dim3(Bb * NPARTS), dim3(256), 0, stream>>>(q, kc, vc, bt, cl, ws);
    attn_reduce<<<dim3(Bb * 4), dim3(256), 0, stream>>>(ws, cl, out);
}

// Round 7
// 149.695 us; speedup vs baseline: 5.5619x; 5.5619x over previous
//
#include <hip/hip_runtime.h>

// Paged attention decode, GQA: B=32, H=32, KVH=8 (G=4), D=128, pages of 16.
// R7 = R4 layout + restored register ping-pong + high occupancy, no LDS.
//  - One block per (b, part=64 tokens); 256 threads span a full 4KB token row
//    (t -> kvh = t>>5, dims (t&31)*4), so each physical page is read exactly
//    once, contiguously, by one block.
//  - 4-token chunks, rolled even/odd register double-buffer (static names):
//    next chunk's 8 float4 loads are in flight during current chunk's compute.
//  - No LDS, no barriers; scores reduced by 5-step shfl_xor butterfly within
//    32-lane kvh groups (VALUBusy measured 7% in R6 -> VALU is not the limit).
//  - __launch_bounds__(256,3): cap ~170 VGPR -> 3 waves/SIMD = 12 waves/CU;
//    hiding: 2 co-resident waves x ~700cy compute >= ~900cy HBM latency.

constexpr int Dh   = 128;
constexpr int Gq   = 4;
constexpr int KVH  = 8;
constexpr int Hq   = 32;
constexpr int Bb   = 32;
constexpr int MB   = 256;
constexpr int PAGE = 16;
constexpr float SCALE = 0.08838834764831845f;

constexpr int NPARTS      = 64;
constexpr int PART_TOKENS = 64;                  // 4 pages per part
constexpr int PG_FLOATS   = PAGE * KVH * Dh;     // 16384 floats = 64 KB
constexpr int ROW_FLOATS  = KVH * Dh;            // 1024 floats per token row

// per-(b,part) workspace floats: acc[32 heads][128] + m[32] + l[32]
constexpr int PART_STRIDE = Hq * Dh + 2 * Hq;    // 4160

struct QuadR { float4 k[4], v[4]; };             // 4 tokens x 4 dims of K and V

__global__ __launch_bounds__(256, 3)
void attn_partial(const float* __restrict__ q,
                  const float* __restrict__ kc,
                  const float* __restrict__ vc,
                  const int*   __restrict__ bt,
                  const int*   __restrict__ cl,
                  float*       __restrict__ ws)
{
    const int part = blockIdx.x & (NPARTS - 1);
    const int b    = blockIdx.x >> 6;

    const int ctx    = cl[b];
    const int pstart = part * PART_TOKENS;
    if (pstart >= ctx) return;
    const int n  = min(PART_TOKENS, ctx - pstart);
    const int TC = (n + 3) >> 2;                 // 4-token chunks, 1..16

    const int t      = threadIdx.x;              // 0..255
    const int kvh    = t >> 5;
    const int lane32 = t & 31;
    const int doff   = lane32 * 4;
    const int t4     = t * 4;

    // prefetch the 4 page indices for this part (16B aligned)
    const int4 pg = *(const int4*)(bt + b * MB + (pstart >> 4));

    // Q fragments, pre-scaled: head (kvh,g), dims [doff, doff+4)
    float4 qv[Gq];
    {
        const float* qbase = q + (size_t)(b * Hq + kvh * Gq) * Dh + doff;
        #pragma unroll
        for (int g = 0; g < Gq; ++g) {
            float4 x = *(const float4*)(qbase + g * Dh);
            qv[g] = make_float4(x.x * SCALE, x.y * SCALE, x.z * SCALE, x.w * SCALE);
        }
    }

    float4 acc[Gq];
    float  m_run[Gq], l_run[Gq];
    #pragma unroll
    for (int g = 0; g < Gq; ++g) {
        acc[g] = make_float4(0.f, 0.f, 0.f, 0.f);
        m_run[g] = -1e30f;
        l_run[g] = 0.f;
    }

    // page index of chunk c via cndmask chain (no memory-indexed array)
    auto physof = [&](int c) -> int {
        const int p = c >> 2;
        return p == 0 ? pg.x : (p == 1 ? pg.y : (p == 2 ? pg.z : pg.w));
    };

    auto LOADQ = [&](QuadR& H, int c) {
        const size_t off = (size_t)physof(c) * PG_FLOATS
                         + (size_t)((c & 3) * 4) * ROW_FLOATS + t4;
        const float* kp = kc + off;
        const float* vp = vc + off;
        #pragma unroll
        for (int j = 0; j < 4; ++j) {
            H.k[j] = *(const float4*)(kp + j * ROW_FLOATS);
            H.v[j] = *(const float4*)(vp + j * ROW_FLOATS);
        }
    };

    auto COMPUTEQ = [&](const QuadR& H, int c) {
        const int tb = c * 4;
        float s[4][Gq];
        #pragma unroll
        for (int j = 0; j < 4; ++j) {
            const bool vj = (tb + j) < n;
            #pragma unroll
            for (int g = 0; g < Gq; ++g) {
                float d = H.k[j].x * qv[g].x + H.k[j].y * qv[g].y
                        + H.k[j].z * qv[g].z + H.k[j].w * qv[g].w;
                d += __shfl_xor(d, 1);
                d += __shfl_xor(d, 2);
                d += __shfl_xor(d, 4);
                d += __shfl_xor(d, 8);
                d += __shfl_xor(d, 16);          // full dot in all 32 lanes
                s[j][g] = vj ? d : -1e30f;
            }
        }
        #pragma unroll
        for (int g = 0; g < Gq; ++g) {
            const float tm = fmaxf(fmaxf(s[0][g], s[1][g]), fmaxf(s[2][g], s[3][g]));
            const float mn    = fmaxf(m_run[g], tm);
            const float alpha = __expf(m_run[g] - mn);
            m_run[g] = mn;
            const float p0 = __expf(s[0][g] - mn);
            const float p1 = __expf(s[1][g] - mn);
            const float p2 = __expf(s[2][g] - mn);
            const float p3 = __expf(s[3][g] - mn);
            l_run[g] = l_run[g] * alpha + (p0 + p1 + p2 + p3);
            acc[g].x = fmaf(p3, H.v[3].x, fmaf(p2, H.v[2].x,
                       fmaf(p1, H.v[1].x, fmaf(p0, H.v[0].x, acc[g].x * alpha))));
            acc[g].y = fmaf(p3, H.v[3].y, fmaf(p2, H.v[2].y,
                       fmaf(p1, H.v[1].y, fmaf(p0, H.v[0].y, acc[g].y * alpha))));
            acc[g].z = fmaf(p3, H.v[3].z, fmaf(p2, H.v[2].z,
                       fmaf(p1, H.v[1].z, fmaf(p0, H.v[0].z, acc[g].z * alpha))));
            acc[g].w = fmaf(p3, H.v[3].w, fmaf(p2, H.v[2].w,
                       fmaf(p1, H.v[1].w, fmaf(p0, H.v[0].w, acc[g].w * alpha))));
        }
    };

    // rolled even/odd ping-pong: next chunk's loads fly during current compute
    QuadR A, B;
    LOADQ(A, 0);
    int c = 0;
    while (true) {
        if (c + 1 < TC) LOADQ(B, c + 1);
        COMPUTEQ(A, c);
        ++c; if (c >= TC) break;
        if (c + 1 < TC) LOADQ(A, c + 1);
        COMPUTEQ(B, c);
        ++c; if (c >= TC) break;
    }

    // write partials: head (kvh,g), dims [doff, doff+4)
    float* wp = ws + (size_t)(b * NPARTS + part) * PART_STRIDE;
    #pragma unroll
    for (int g = 0; g < Gq; ++g)
        *(float4*)(wp + (kvh * Gq + g) * Dh + doff) = acc[g];
    if (lane32 == 0) {
        #pragma unroll
        for (int g = 0; g < Gq; ++g) {
            wp[Hq * Dh + kvh * Gq + g]      = m_run[g];
            wp[Hq * Dh + Hq + kvh * Gq + g] = l_run[g];
        }
    }
}

__global__ __launch_bounds__(256, 4)
void attn_reduce(const float* __restrict__ ws,
                 const int*   __restrict__ cl,
                 float*       __restrict__ out)
{
    const int b       = blockIdx.x >> 2;
    const int quarter = blockIdx.x & 3;
    const int tid     = threadIdx.x;
    const int h       = quarter * 8 + (tid >> 5);
    const int doff    = (tid & 31) * 4;

    const int ctx = cl[b];
    const int np  = min(NPARTS, (ctx + PART_TOKENS - 1) / PART_TOKENS);

    const float* base = ws + (size_t)b * NPARTS * PART_STRIDE;

    float m = -1e30f;
    for (int p = 0; p < np; ++p)
        m = fmaxf(m, base[p * PART_STRIDE + Hq * Dh + h]);

    float L = 0.f;
    float ax = 0.f, ay = 0.f, az = 0.f, aw = 0.f;
    for (int p = 0; p < np; ++p) {
        const float* bp = base + p * PART_STRIDE;
        const float c = __expf(bp[Hq * Dh + h] - m);
        L += bp[Hq * Dh + Hq + h] * c;
        const float4 v = *(const float4*)(bp + h * Dh + doff);
        ax = fmaf(c, v.x, ax);
        ay = fmaf(c, v.y, ay);
        az = fmaf(c, v.z, az);
        aw = fmaf(c, v.w, aw);
    }
    const float inv = 1.f / L;
    float* op = out + (size_t)(b * Hq + h) * Dh + doff;
    *(float4*)op = make_float4(ax * inv, ay * inv, az * inv, aw * inv);
}

extern "C" void kernel_launch(void* const* d_in, const int* in_sizes, int n_in,
                              void* d_out, int out_size, void* d_ws, size_t ws_size,
                              hipStream_t stream) {
    const float* q  = (const float*)d_in[0];
    const float* kc = (const float*)d_in[1];
    const float* vc = (const float*)d_in[2];
    const int*   bt = (const int*)d_in[3];
    const int*   cl = (const int*)d_in[4];
    float* out = (float*)d_out;
    float* ws  = (float*)d_ws;

    attn_partial<<<dim3(Bb * NPARTS), dim3(256), 0, stream>>>(q, kc, vc, bt, cl, ws);
    attn_reduce<<<dim3(Bb * 4), dim3(256), 0, stream>>>(ws, cl, out);
}